// Round 3
// baseline (303.927 us; speedup 1.0000x reference)
//
#include <hip/hip_runtime.h>

#define BATCH 8192
#define DIN 4096
#define DH 512

typedef float f32x4 __attribute__((ext_vector_type(4)));
typedef float f32x2 __attribute__((ext_vector_type(2)));
typedef short s16x8 __attribute__((ext_vector_type(8)));
typedef unsigned short u16x4 __attribute__((ext_vector_type(4)));
typedef unsigned short u16x8 __attribute__((ext_vector_type(8)));

// round-to-nearest-even f32 -> bf16 bits
static __device__ __forceinline__ unsigned short f2bf(float f) {
  unsigned int u = __float_as_uint(f);
  u += 0x7FFFu + ((u >> 16) & 1u);
  return (unsigned short)(u >> 16);
}

// ---------- f32 [R][C] -> bf16 out[(row_off+c)*ldo + r] (i.e. transpose) ----------
__global__ __launch_bounds__(256) void transpose_bf16_k(
    const float* __restrict__ in, int R, int C,
    unsigned short* __restrict__ out, int ldo, int row_off)
{
  __shared__ float tl[32][33];
  const int tx = threadIdx.x, ty = threadIdx.y;
  const int c0 = blockIdx.x * 32, r0 = blockIdx.y * 32;
#pragma unroll
  for (int i = 0; i < 4; i++)
    tl[ty + 8 * i][tx] = in[(size_t)(r0 + ty + 8 * i) * C + c0 + tx];
  __syncthreads();
#pragma unroll
  for (int i = 0; i < 4; i++)
    out[(size_t)(row_off + c0 + ty + 8 * i) * ldo + r0 + tx] = f2bf(tl[tx][ty + 8 * i]);
}

// ---------- elementwise f32 -> bf16 (exact grid, 4 elems/thread) ----------
__global__ __launch_bounds__(256) void cast_bf16_k(
    const float* __restrict__ in, unsigned short* __restrict__ out)
{
  const int i = (blockIdx.x * 256 + threadIdx.x) * 4;
  f32x4 v = *(const f32x4*)(in + i);
  u16x4 p = { f2bf(v[0]), f2bf(v[1]), f2bf(v[2]), f2bf(v[3]) };
  *(u16x4*)(out + i) = p;
}

// ---------- zero-fill bf16 region [rows][cols8*8] with leading dim ld ----------
__global__ __launch_bounds__(256) void zfill_k(
    unsigned short* __restrict__ base, int ld, int rows, int cols8)
{
  const int gid = blockIdx.x * 256 + threadIdx.x;
  const int row = gid / cols8;
  const int c = (gid % cols8) * 8;
  if (row < rows) {
    u16x8 z = { 0, 0, 0, 0, 0, 0, 0, 0 };
    *(u16x8*)(base + (size_t)row * ld + c) = z;
  }
}

// ---------- GEMM: C[M][N] = concat_K(A0,A1) @ BT^T, f32 sources, bf16 MFMA ----------
// Tile 128 x BN, BK=32. 4 waves (2x2), per-wave 64 x BN/2 = 4 x FRN frags of 16x16.
// EPI: 0 = +bias; 1 = +bias then scale transforms (tau/A_row/B_col); 2 = raw;
//      3 = +bias only for col<DH (fused G1|GB output).
template<int BN, int EPI>
__global__ __launch_bounds__(256) void gemm_k(
    const float* __restrict__ A0, int lda0, int K0,
    const float* __restrict__ A1, int lda1, int K1,
    const unsigned short* __restrict__ BT,
    float* __restrict__ C, int ldc,
    const float* __restrict__ bias,
    const float* __restrict__ base_tau)
{
  constexpr int FRN = BN / 32;
  __shared__ unsigned short Asm_[128][32];
  __shared__ unsigned short Bsm_[BN][32];

  const int tid = threadIdx.x;
  const int lane = tid & 63;
  const int wid = tid >> 6;
  const int wm = (wid >> 1) * 64;
  const int wn = (wid & 1) * (BN / 2);
  const int mb = blockIdx.y * 128;
  const int nb = blockIdx.x * BN;
  const int K = K0 + K1;

  f32x4 acc[4][FRN];
#pragma unroll
  for (int i = 0; i < 4; i++)
#pragma unroll
    for (int j = 0; j < FRN; j++)
      acc[i][j] = (f32x4){ 0.f, 0.f, 0.f, 0.f };

  const int ar = tid >> 3;        // 0..31 (A stage row, +32*i)
  const int ac = (tid & 7) * 4;   // A stage col
  const int br = tid >> 2;        // 0..63 (B stage row, +64*i)
  const int bc = (tid & 3) * 8;   // B stage col
  const int fr = lane & 15;       // fragment row/col within 16
  const int fk = (lane >> 4) * 8; // fragment k-octet

  for (int k0 = 0; k0 < K; k0 += 32) {
    // stage A: 128x32 f32 -> bf16 (two source segments along K; k0 multiple of
    // 32 and K0 multiple of 32 => segment uniform within a tile column)
#pragma unroll
    for (int i = 0; i < 4; i++) {
      const int r = ar + i * 32;
      const int gk = k0 + ac;
      const float* src = (gk < K0)
          ? (A0 + (size_t)(mb + r) * lda0 + gk)
          : (A1 + (size_t)(mb + r) * lda1 + (gk - K0));
      f32x4 v = *(const f32x4*)src;
      u16x4 p = { f2bf(v[0]), f2bf(v[1]), f2bf(v[2]), f2bf(v[3]) };
      *(u16x4*)&Asm_[r][ac] = p;
    }
    // stage B: BNx32 bf16 copy
#pragma unroll
    for (int i = 0; i < BN / 64; i++) {
      const int r = br + i * 64;
      *(u16x8*)&Bsm_[r][bc] = *(const u16x8*)(BT + (size_t)(nb + r) * K + k0 + bc);
    }
    __syncthreads();

    s16x8 af[4], bfv[FRN];
#pragma unroll
    for (int mi = 0; mi < 4; mi++)
      af[mi] = *(const s16x8*)&Asm_[wm + mi * 16 + fr][fk];
#pragma unroll
    for (int ni = 0; ni < FRN; ni++)
      bfv[ni] = *(const s16x8*)&Bsm_[wn + ni * 16 + fr][fk];
#pragma unroll
    for (int mi = 0; mi < 4; mi++)
#pragma unroll
      for (int ni = 0; ni < FRN; ni++)
        acc[mi][ni] = __builtin_amdgcn_mfma_f32_16x16x32_bf16(
            af[mi], bfv[ni], acc[mi][ni], 0, 0, 0);
    __syncthreads();
  }

  const int rb = (lane >> 4) * 4;
#pragma unroll
  for (int mi = 0; mi < 4; mi++) {
#pragma unroll
    for (int ni = 0; ni < FRN; ni++) {
#pragma unroll
      for (int r = 0; r < 4; r++) {
        const int row = mb + wm + mi * 16 + rb + r;
        const int col = nb + wn + ni * 16 + fr;
        float v = acc[mi][ni][r];
        if (EPI == 0) {
          v += bias[col];
        } else if (EPI == 1) {
          v += bias[col];
          const int cm = col & (DH - 1);
          if ((col >> 9) == 0) {
            const float s = 1.0f / (1.0f + expf(-v));
            v = 1.0f / (base_tau[cm] * 2.0f * s + 1e-8f);   // tau_inv
          } else {
            v = 1.0f + 0.5f * tanhf(v);                      // A_row / B_col
          }
        } else if (EPI == 3) {
          if (col < DH) v += bias[col];
        }
        C[(size_t)row * ldc + col] = v;
      }
    }
  }
}

// ---------- block-wide sum over 256 threads (4 waves) ----------
__device__ __forceinline__ float block_sum256(float v, float* red) {
#pragma unroll
  for (int m = 32; m >= 1; m >>= 1) v += __shfl_xor(v, m, 64);
  __syncthreads();
  if ((threadIdx.x & 63) == 0) red[threadIdx.x >> 6] = v;
  __syncthreads();
  return red[0] + red[1] + red[2] + red[3];
}

// ---------- t = gelu_exact(LN(pre[:, :512])) ----------
__global__ __launch_bounds__(256) void ln_gelu_k(
    const float* __restrict__ pre, int ldp,
    const float* __restrict__ g, const float* __restrict__ b,
    float* __restrict__ t)
{
  __shared__ float red[4];
  const int row = blockIdx.x;
  const int c = threadIdx.x * 2;
  f32x2 v = *(const f32x2*)(pre + (size_t)row * ldp + c);
  const float mu = block_sum256(v[0] + v[1], red) * (1.0f / DH);
  const float d0 = v[0] - mu, d1 = v[1] - mu;
  const float var = block_sum256(d0 * d0 + d1 * d1, red) * (1.0f / DH);
  const float inv = rsqrtf(var + 1e-5f);
  const float y0 = d0 * inv * g[c] + b[c];
  const float y1 = d1 * inv * g[c + 1] + b[c + 1];
  f32x2 o = { 0.5f * y0 * (1.0f + erff(y0 * 0.70710678118f)),
              0.5f * y1 * (1.0f + erff(y1 * 0.70710678118f)) };
  *(f32x2*)(t + (size_t)row * DH + c) = o;
}

// ---------- new_h = LN(h + dt*(-h*tauinv + tanh(rawA*arow + rawB*bcol))) ----------
// OUTPUT IS F32 (reference returns float32).
__global__ __launch_bounds__(256) void final_k(
    const float* __restrict__ h,
    const float* __restrict__ rawA, int lda,
    const float* __restrict__ rawB, int ldb,
    const float* __restrict__ scales,
    const float* __restrict__ hn_g, const float* __restrict__ hn_b,
    float* __restrict__ out)
{
  __shared__ float red[4];
  const int row = blockIdx.x;
  const int c = threadIdx.x * 2;
  const size_t ro = (size_t)row * DH;
  f32x2 hv = *(const f32x2*)(h + ro + c);
  f32x2 ra = *(const f32x2*)(rawA + (size_t)row * lda + c);
  f32x2 rb = *(const f32x2*)(rawB + (size_t)row * ldb + c);
  const float* sc = scales + (size_t)row * (3 * DH);
  f32x2 ti  = *(const f32x2*)(sc + c);
  f32x2 arw = *(const f32x2*)(sc + DH + c);
  f32x2 bcl = *(const f32x2*)(sc + 2 * DH + c);
  const float u0 = hv[0] + 0.1f * (-hv[0] * ti[0] + tanhf(ra[0] * arw[0] + rb[0] * bcl[0]));
  const float u1 = hv[1] + 0.1f * (-hv[1] * ti[1] + tanhf(ra[1] * arw[1] + rb[1] * bcl[1]));
  const float mu = block_sum256(u0 + u1, red) * (1.0f / DH);
  const float d0 = u0 - mu, d1 = u1 - mu;
  const float var = block_sum256(d0 * d0 + d1 * d1, red) * (1.0f / DH);
  const float inv = rsqrtf(var + 1e-5f);
  f32x2 o = { d0 * inv * hn_g[c] + hn_b[c],
              d1 * inv * hn_g[c + 1] + hn_b[c + 1] };
  *(f32x2*)(out + ro + c) = o;
}

extern "C" void kernel_launch(void* const* d_in, const int* in_sizes, int n_in,
                              void* d_out, int out_size, void* d_ws, size_t ws_size,
                              hipStream_t stream)
{
  const float* x        = (const float*)d_in[0];
  const float* h        = (const float*)d_in[1];
  const float* W1       = (const float*)d_in[2];
  const float* b1       = (const float*)d_in[3];
  const float* ln1_g    = (const float*)d_in[4];
  const float* ln1_b    = (const float*)d_in[5];
  const float* W2       = (const float*)d_in[6];
  const float* b2       = (const float*)d_in[7];
  const float* base_tau = (const float*)d_in[8];
  const float* base_A   = (const float*)d_in[9];
  const float* base_B   = (const float*)d_in[10];
  const float* hn_g     = (const float*)d_in[11];
  const float* hn_b     = (const float*)d_in[12];

  const int KC = DIN + DH;  // 4608
  char* w = (char*)d_ws;
  // ws layout (bytes):
  unsigned short* BTcat  = (unsigned short*)(w);              // [1024][4608] bf16 = 9,437,184
  unsigned short* W2T    = (unsigned short*)(w + 9437184);    // [1536][512]  bf16 = 1,572,864
  unsigned short* Abf    = (unsigned short*)(w + 11010048);   // [512][512]   bf16 =   524,288
  float*          preAB  = (float*)(w + 11534336);            // [8192][1024] f32  = 33,554,432
  float*          t      = (float*)(w + 45088768);            // [8192][512]  f32  = 16,777,216
  float*          scales = (float*)(w + 61865984);            // [8192][1536] f32  = 50,331,648
  float*          rawA   = (float*)(w + 112197632);           // [8192][512]  f32  = 16,777,216
  // total: 128,974,848 bytes

  dim3 tb(32, 8);
  // BTcat rows 0..511 = W1^T (full K=4608)
  transpose_bf16_k<<<dim3(DH / 32, KC / 32), tb, 0, stream>>>(W1, KC, DH, BTcat, KC, 0);
  // BTcat rows 512..1023, k<4096 = base_B^T; k in [4096,4608) = 0
  transpose_bf16_k<<<dim3(DH / 32, DIN / 32), tb, 0, stream>>>(base_B, DIN, DH, BTcat, KC, DH);
  zfill_k<<<128, 256, 0, stream>>>(BTcat + (size_t)DH * KC + DIN, KC, DH, DH / 8);
  transpose_bf16_k<<<dim3(3 * DH / 32, DH / 32), tb, 0, stream>>>(W2, DH, 3 * DH, W2T, DH, 0);
  cast_bf16_k<<<DH * DH / 1024, 256, 0, stream>>>(base_A, Abf);

  // fused G1|GB: [x|h] @ [W1 | base_B(0-padded)] -> preAB [8192][1024]
  gemm_k<128, 3><<<dim3(1024 / 128, BATCH / 128), 256, 0, stream>>>(
      x, DIN, DIN, h, DH, DH, BTcat, preAB, 1024, b1, nullptr);
  // rawA = h @ base_A^T  (BT == base_A row-major, bf16-cast)
  gemm_k<64, 2><<<dim3(DH / 64, BATCH / 128), 256, 0, stream>>>(
      h, DH, DH, nullptr, 0, 0, Abf, rawA, DH, nullptr, nullptr);
  // t = gelu(LN(preAB[:, :512]))
  ln_gelu_k<<<BATCH, 256, 0, stream>>>(preAB, 1024, ln1_g, ln1_b, t);
  // scales = transforms(t @ W2 + b2): [tau_inv | A_row | B_col]
  gemm_k<128, 1><<<dim3(3 * DH / 128, BATCH / 128), 256, 0, stream>>>(
      t, DH, DH, nullptr, 0, 0, W2T, scales, 3 * DH, b2, base_tau);
  // final: dhdt + LN -> f32 out
  final_k<<<BATCH, 256, 0, stream>>>(h, rawA, DH, preAB + DH, 1024, scales,
                                     hn_g, hn_b, (float*)d_out);
}

// Round 4
// 263.905 us; speedup vs baseline: 1.1517x; 1.1517x over previous
//
#include <hip/hip_runtime.h>

#define BATCH 8192
#define DIN 4096
#define DH 512

typedef float f32x4 __attribute__((ext_vector_type(4)));
typedef float f32x2 __attribute__((ext_vector_type(2)));
typedef short s16x8 __attribute__((ext_vector_type(8)));
typedef unsigned short u16x2 __attribute__((ext_vector_type(2)));
typedef unsigned short u16x4 __attribute__((ext_vector_type(4)));
typedef unsigned short u16x8 __attribute__((ext_vector_type(8)));

// round-to-nearest-even f32 -> bf16 bits
static __device__ __forceinline__ unsigned short f2bf(float f) {
  unsigned int u = __float_as_uint(f);
  u += 0x7FFFu + ((u >> 16) & 1u);
  return (unsigned short)(u >> 16);
}
static __device__ __forceinline__ float bf2f(unsigned short s) {
  return __uint_as_float(((unsigned int)s) << 16);
}

typedef const __attribute__((address_space(1))) unsigned int* gas_ptr;
typedef __attribute__((address_space(3))) unsigned int* las_ptr;
// async global->LDS, 16B per lane; LDS dest = uniform base + lane*16
static __device__ __forceinline__ void gl_lds16(const unsigned short* g, unsigned short* l) {
  __builtin_amdgcn_global_load_lds((gas_ptr)g, (las_ptr)l, 16, 0, 0);
}

// ---------- elementwise f32 -> bf16 (exact grid, 4 elems/thread) ----------
__global__ __launch_bounds__(256) void cast_bf16_k(
    const float* __restrict__ in, unsigned short* __restrict__ out)
{
  const int i = (blockIdx.x * 256 + threadIdx.x) * 4;
  f32x4 v = *(const f32x4*)(in + i);
  u16x4 p = { f2bf(v[0]), f2bf(v[1]), f2bf(v[2]), f2bf(v[3]) };
  *(u16x4*)(out + i) = p;
}

// ---------- f32 [R][C] -> bf16 out[(row_off+c)*ldo + r] (transpose) ----------
__global__ __launch_bounds__(256) void transpose_bf16_k(
    const float* __restrict__ in, int R, int C,
    unsigned short* __restrict__ out, int ldo, int row_off)
{
  __shared__ float tl[32][33];
  const int tx = threadIdx.x, ty = threadIdx.y;
  const int c0 = blockIdx.x * 32, r0 = blockIdx.y * 32;
#pragma unroll
  for (int i = 0; i < 4; i++)
    tl[ty + 8 * i][tx] = in[(size_t)(r0 + ty + 8 * i) * C + c0 + tx];
  __syncthreads();
#pragma unroll
  for (int i = 0; i < 4; i++)
    out[(size_t)(row_off + c0 + ty + 8 * i) * ldo + r0 + tx] = f2bf(tl[tx][ty + 8 * i]);
}

// ---------- zero-fill bf16 region ----------
__global__ __launch_bounds__(256) void zfill_k(
    unsigned short* __restrict__ base, int ld, int rows, int cols8)
{
  const int gid = blockIdx.x * 256 + threadIdx.x;
  const int row = gid / cols8;
  const int c = (gid % cols8) * 8;
  if (row < rows) {
    u16x8 z = { 0, 0, 0, 0, 0, 0, 0, 0 };
    *(u16x8*)(base + (size_t)row * ld + c) = z;
  }
}

// ---------------------------------------------------------------------------
// m97-style GEMM: C = concat_K(A0,A1) @ BT^T. A,BT bf16. 128x128 tile, BK=32,
// 4 waves (2x2, 64x64 each, 4x4 frags of 16x16x32), global_load_lds staging.
// EPI: 1 = +bias then scale transforms -> C0 (ldc=1536)
//      2 = raw -> C0 (ldc)
//      3 = split: col<512 -> C0 +bias ; col>=512 -> C1 raw (both ld 512)
// SWZ: XCD-chunked block swizzle (grid must be 8*64*k; here 512).
// Grid: 1-D, nx*64 blocks; by = virt%64 (M), bx = virt/64 (N).
// ---------------------------------------------------------------------------
template<int EPI, bool SWZ>
__global__ __launch_bounds__(256) void gemm_lds_k(
    const unsigned short* __restrict__ A0, int lda0, int K0,
    const unsigned short* __restrict__ A1, int lda1, int K1,
    const unsigned short* __restrict__ BT, int ldb,
    unsigned short* __restrict__ C0, int ldc,
    unsigned short* __restrict__ C1,
    const float* __restrict__ bias,
    const float* __restrict__ base_tau)
{
  __shared__ unsigned short Asm_[128][32];   // 8 KB, linear (gload_lds dest)
  __shared__ unsigned short Bsm_[128][32];   // 8 KB

  const int tid = threadIdx.x;
  const int lane = tid & 63;
  const int wid = tid >> 6;
  const int wm = (wid >> 1) * 64;
  const int wn = (wid & 1) * 64;

  int virt;
  if (SWZ) {
    const int cpx = gridDim.x >> 3;
    virt = (blockIdx.x & 7) * cpx + (blockIdx.x >> 3);
  } else {
    virt = blockIdx.x;
  }
  const int by = virt & 63;       // BATCH/128 == 64
  const int bx = virt >> 6;
  const int mb = by * 128;
  const int nb = bx * 128;
  const int K = K0 + K1;

  f32x4 acc[4][4];
#pragma unroll
  for (int i = 0; i < 4; i++)
#pragma unroll
    for (int j = 0; j < 4; j++)
      acc[i][j] = (f32x4){ 0.f, 0.f, 0.f, 0.f };

  const int srow = lane >> 2;          // 0..15 (staging row within 16-row chunk)
  const int scol = (lane & 3) * 8;     // staging col (elements)
  const int fr = lane & 15;            // fragment row/col
  const int fk = (lane >> 4) * 8;      // fragment k-octet

  for (int k0 = 0; k0 < K; k0 += 32) {
    const bool s0 = (k0 < K0);
    const unsigned short* Ab = s0 ? A0 : A1;
    const int ld = s0 ? lda0 : lda1;
    const int ko = (s0 ? k0 : k0 - K0) + scol;
#pragma unroll
    for (int c = 0; c < 2; c++) {
      const int r = 32 * wid + c * 16 + srow;
      gl_lds16(Ab + (size_t)(mb + r) * ld + ko, &Asm_[32 * wid + c * 16][0]);
      gl_lds16(BT + (size_t)(nb + r) * ldb + k0 + scol, &Bsm_[32 * wid + c * 16][0]);
    }
    __syncthreads();   // compiler drains vmcnt before barrier

    s16x8 af[4], bfv[4];
#pragma unroll
    for (int mi = 0; mi < 4; mi++)
      af[mi] = *(const s16x8*)&Asm_[wm + mi * 16 + fr][fk];
#pragma unroll
    for (int ni = 0; ni < 4; ni++)
      bfv[ni] = *(const s16x8*)&Bsm_[wn + ni * 16 + fr][fk];
#pragma unroll
    for (int mi = 0; mi < 4; mi++)
#pragma unroll
      for (int ni = 0; ni < 4; ni++)
        acc[mi][ni] = __builtin_amdgcn_mfma_f32_16x16x32_bf16(
            af[mi], bfv[ni], acc[mi][ni], 0, 0, 0);
    __syncthreads();
  }

  const int rb = (lane >> 4) * 4;
#pragma unroll
  for (int mi = 0; mi < 4; mi++) {
#pragma unroll
    for (int ni = 0; ni < 4; ni++) {
#pragma unroll
      for (int r = 0; r < 4; r++) {
        const int row = mb + wm + mi * 16 + rb + r;
        const int col = nb + wn + ni * 16 + fr;
        float v = acc[mi][ni][r];
        if (EPI == 3) {
          if (col < DH) C0[(size_t)row * DH + col] = f2bf(v + bias[col]);
          else          C1[(size_t)row * DH + (col - DH)] = f2bf(v);
        } else if (EPI == 2) {
          C0[(size_t)row * ldc + col] = f2bf(v);
        } else if (EPI == 1) {
          v += bias[col];
          if ((col >> 9) == 0) {
            const float s = 1.0f / (1.0f + expf(-v));
            v = 1.0f / (base_tau[col & (DH - 1)] * 2.0f * s + 1e-8f);  // tau_inv
          } else {
            v = 1.0f + 0.5f * tanhf(v);                                 // A_row/B_col
          }
          C0[(size_t)row * ldc + col] = f2bf(v);
        }
      }
    }
  }
}

// ---------- block-wide sum over 256 threads (4 waves) ----------
__device__ __forceinline__ float block_sum256(float v, float* red) {
#pragma unroll
  for (int m = 32; m >= 1; m >>= 1) v += __shfl_xor(v, m, 64);
  __syncthreads();
  if ((threadIdx.x & 63) == 0) red[threadIdx.x >> 6] = v;
  __syncthreads();
  return red[0] + red[1] + red[2] + red[3];
}

// ---------- t = bf16(gelu_exact(LN(pre1))), pre1 bf16 [8192][512] ----------
__global__ __launch_bounds__(256) void ln_gelu_k(
    const unsigned short* __restrict__ pre,
    const float* __restrict__ g, const float* __restrict__ b,
    unsigned short* __restrict__ t)
{
  __shared__ float red[4];
  const int row = blockIdx.x;
  const int c = threadIdx.x * 2;
  const size_t ro = (size_t)row * DH;
  u16x2 raw = *(const u16x2*)(pre + ro + c);
  const float v0 = bf2f(raw[0]), v1 = bf2f(raw[1]);
  const float mu = block_sum256(v0 + v1, red) * (1.0f / DH);
  const float d0 = v0 - mu, d1 = v1 - mu;
  const float var = block_sum256(d0 * d0 + d1 * d1, red) * (1.0f / DH);
  const float inv = rsqrtf(var + 1e-5f);
  const float y0 = d0 * inv * g[c] + b[c];
  const float y1 = d1 * inv * g[c + 1] + b[c + 1];
  u16x2 o = { f2bf(0.5f * y0 * (1.0f + erff(y0 * 0.70710678118f))),
              f2bf(0.5f * y1 * (1.0f + erff(y1 * 0.70710678118f))) };
  *(u16x2*)(t + ro + c) = o;
}

// ---------- new_h = LN(h + dt*(-h*tauinv + tanh(rawA*arow + rawB*bcol))) ----------
// rawA/rawB/scales bf16; h f32; OUT f32.
__global__ __launch_bounds__(256) void final_k(
    const float* __restrict__ h,
    const unsigned short* __restrict__ rawA,
    const unsigned short* __restrict__ rawB,
    const unsigned short* __restrict__ scales,
    const float* __restrict__ hn_g, const float* __restrict__ hn_b,
    float* __restrict__ out)
{
  __shared__ float red[4];
  const int row = blockIdx.x;
  const int c = threadIdx.x * 2;
  const size_t ro = (size_t)row * DH;
  f32x2 hv = *(const f32x2*)(h + ro + c);
  u16x2 ra = *(const u16x2*)(rawA + ro + c);
  u16x2 rb = *(const u16x2*)(rawB + ro + c);
  const unsigned short* sc = scales + (size_t)row * (3 * DH);
  u16x2 ti  = *(const u16x2*)(sc + c);
  u16x2 arw = *(const u16x2*)(sc + DH + c);
  u16x2 bcl = *(const u16x2*)(sc + 2 * DH + c);
  const float u0 = hv[0] + 0.1f * (-hv[0] * bf2f(ti[0])
                 + tanhf(bf2f(ra[0]) * bf2f(arw[0]) + bf2f(rb[0]) * bf2f(bcl[0])));
  const float u1 = hv[1] + 0.1f * (-hv[1] * bf2f(ti[1])
                 + tanhf(bf2f(ra[1]) * bf2f(arw[1]) + bf2f(rb[1]) * bf2f(bcl[1])));
  const float mu = block_sum256(u0 + u1, red) * (1.0f / DH);
  const float d0 = u0 - mu, d1 = u1 - mu;
  const float var = block_sum256(d0 * d0 + d1 * d1, red) * (1.0f / DH);
  const float inv = rsqrtf(var + 1e-5f);
  f32x2 o = { d0 * inv * hn_g[c] + hn_b[c],
              d1 * inv * hn_g[c + 1] + hn_b[c + 1] };
  *(f32x2*)(out + ro + c) = o;
}

extern "C" void kernel_launch(void* const* d_in, const int* in_sizes, int n_in,
                              void* d_out, int out_size, void* d_ws, size_t ws_size,
                              hipStream_t stream)
{
  const float* x        = (const float*)d_in[0];
  const float* h        = (const float*)d_in[1];
  const float* W1       = (const float*)d_in[2];   // [4608][512]
  const float* b1       = (const float*)d_in[3];
  const float* ln1_g    = (const float*)d_in[4];
  const float* ln1_b    = (const float*)d_in[5];
  const float* W2       = (const float*)d_in[6];   // [512][1536]
  const float* b2       = (const float*)d_in[7];
  const float* base_tau = (const float*)d_in[8];
  const float* base_A   = (const float*)d_in[9];   // [512][512]
  const float* base_B   = (const float*)d_in[10];  // [4096][512]
  const float* hn_g     = (const float*)d_in[11];
  const float* hn_b     = (const float*)d_in[12];

  const int KC = DIN + DH;  // 4608
  char* w = (char*)d_ws;
  // ws layout (bytes), total 128,974,848 (== proven-safe round-1 footprint):
  unsigned short* xbf    = (unsigned short*)(w);               // [8192][4096] 67,108,864
  unsigned short* hbf    = (unsigned short*)(w + 67108864);    // [8192][512]   8,388,608
  unsigned short* BTcat  = (unsigned short*)(w + 75497472);    // [1024][4608]  9,437,184
  unsigned short* tbf    = (unsigned short*)(w + 75497472);    // [8192][512] ALIAS over BTcat (dead after fused GEMM)
  unsigned short* W2T    = (unsigned short*)(w + 84934656);    // [1536][512]   1,572,864
  unsigned short* Abf    = (unsigned short*)(w + 86507520);    // [512][512]      524,288
  unsigned short* pre1   = (unsigned short*)(w + 87031808);    // [8192][512]   8,388,608
  unsigned short* rawA   = (unsigned short*)(w + 87031808);    // ALIAS over pre1 (dead after ln_gelu)
  unsigned short* rawB   = (unsigned short*)(w + 95420416);    // [8192][512]   8,388,608
  unsigned short* scales = (unsigned short*)(w + 103809024);   // [8192][1536] 25,165,824

  // ---- prep: casts + weight transposes ----
  cast_bf16_k<<<DIN * BATCH / 1024, 256, 0, stream>>>(x, xbf);
  cast_bf16_k<<<DH * BATCH / 1024, 256, 0, stream>>>(h, hbf);
  cast_bf16_k<<<DH * DH / 1024, 256, 0, stream>>>(base_A, Abf);
  dim3 tb(32, 8);
  transpose_bf16_k<<<dim3(DH / 32, KC / 32), tb, 0, stream>>>(W1, KC, DH, BTcat, KC, 0);
  transpose_bf16_k<<<dim3(DH / 32, DIN / 32), tb, 0, stream>>>(base_B, DIN, DH, BTcat, KC, DH);
  zfill_k<<<128, 256, 0, stream>>>(BTcat + (size_t)DH * KC + DIN, KC, DH, DH / 8);
  transpose_bf16_k<<<dim3(3 * DH / 32, DH / 32), tb, 0, stream>>>(W2, DH, 3 * DH, W2T, DH, 0);

  // ---- fused G1|GB: [x|h] @ [W1 | base_B~]  -> pre1, rawB (bf16) ----
  gemm_lds_k<3, true><<<512, 256, 0, stream>>>(
      xbf, DIN, DIN, hbf, DH, DH, BTcat, KC, pre1, DH, rawB, b1, nullptr);
  // ---- t = gelu(LN(pre1)) -> tbf (over BTcat region) ----
  ln_gelu_k<<<BATCH, 256, 0, stream>>>(pre1, ln1_g, ln1_b, tbf);
  // ---- rawA = h @ base_A^T (over pre1 region) ----
  gemm_lds_k<2, false><<<256, 256, 0, stream>>>(
      hbf, DH, DH, nullptr, 0, 0, Abf, DH, rawA, DH, nullptr, nullptr, nullptr);
  // ---- scales = transforms(t @ W2 + b2) ----
  gemm_lds_k<1, false><<<768, 256, 0, stream>>>(
      tbf, DH, DH, nullptr, 0, 0, W2T, DH, scales, 3 * DH, nullptr, b2, base_tau);
  // ---- final: dhdt + LN -> f32 out ----
  final_k<<<BATCH, 256, 0, stream>>>(h, rawA, rawB, scales, hn_g, hn_b, (float*)d_out);
}

// Round 5
// 242.042 us; speedup vs baseline: 1.2557x; 1.0903x over previous
//
#include <hip/hip_runtime.h>

#define BATCH 8192
#define DIN 4096
#define DH 512

typedef float f32x4 __attribute__((ext_vector_type(4)));
typedef float f32x2 __attribute__((ext_vector_type(2)));
typedef short s16x8 __attribute__((ext_vector_type(8)));
typedef unsigned short u16x2 __attribute__((ext_vector_type(2)));
typedef unsigned short u16x4 __attribute__((ext_vector_type(4)));
typedef unsigned short u16x8 __attribute__((ext_vector_type(8)));

// round-to-nearest-even f32 -> bf16 bits
static __device__ __forceinline__ unsigned short f2bf(float f) {
  unsigned int u = __float_as_uint(f);
  u += 0x7FFFu + ((u >> 16) & 1u);
  return (unsigned short)(u >> 16);
}
static __device__ __forceinline__ float bf2f(unsigned short s) {
  return __uint_as_float(((unsigned int)s) << 16);
}

typedef const __attribute__((address_space(1))) unsigned int* gas_ptr;
typedef __attribute__((address_space(3))) unsigned int* las_ptr;
// async global->LDS, 16B per lane; LDS dest = uniform base + lane*16
static __device__ __forceinline__ void gl_lds16(const unsigned short* g, unsigned short* l) {
  __builtin_amdgcn_global_load_lds((gas_ptr)g, (las_ptr)l, 16, 0, 0);
}

// ---------- elementwise f32 -> bf16 ----------
__global__ __launch_bounds__(256) void cast_bf16_k(
    const float* __restrict__ in, unsigned short* __restrict__ out)
{
  const int i = (blockIdx.x * 256 + threadIdx.x) * 4;
  f32x4 v = *(const f32x4*)(in + i);
  u16x4 p = { f2bf(v[0]), f2bf(v[1]), f2bf(v[2]), f2bf(v[3]) };
  *(u16x4*)(out + i) = p;
}

// ---------- f32 [R][C] -> bf16 out[(row_off+c)*ldo + r] (transpose) ----------
__global__ __launch_bounds__(256) void transpose_bf16_k(
    const float* __restrict__ in, int R, int C,
    unsigned short* __restrict__ out, int ldo, int row_off)
{
  __shared__ float tl[32][33];
  const int tx = threadIdx.x, ty = threadIdx.y;
  const int c0 = blockIdx.x * 32, r0 = blockIdx.y * 32;
#pragma unroll
  for (int i = 0; i < 4; i++)
    tl[ty + 8 * i][tx] = in[(size_t)(r0 + ty + 8 * i) * C + c0 + tx];
  __syncthreads();
#pragma unroll
  for (int i = 0; i < 4; i++)
    out[(size_t)(row_off + c0 + ty + 8 * i) * ldo + r0 + tx] = f2bf(tl[tx][ty + 8 * i]);
}

// ---------- zero-fill bf16 region ----------
__global__ __launch_bounds__(256) void zfill_k(
    unsigned short* __restrict__ base, int ld, int rows, int cols8)
{
  const int gid = blockIdx.x * 256 + threadIdx.x;
  const int row = gid / cols8;
  const int c = (gid % cols8) * 8;
  if (row < rows) {
    u16x8 z = { 0, 0, 0, 0, 0, 0, 0, 0 };
    *(u16x8*)(base + (size_t)row * ld + c) = z;
  }
}

// ---------------------------------------------------------------------------
// Pipelined GEMM engine (T3/T4): 128x128 tile, BK=32, 3-deep LDS pipeline,
// counted vmcnt (never drains to 0 in main loop), raw s_barrier.
// A,BT bf16. 4 waves (2x2, 64x64 each, 4x4 frags of 16x16x32), gload_lds.
// EPI: 1 = +bias then scale transforms -> C0 (ldc); 2 = raw -> C0;
//      3 = split: col<512 -> C0 +bias ; col>=512 -> C1 raw (both ld 512).
// As/Bs: 3*4096 u16 each (48 KB total).
// ---------------------------------------------------------------------------
template<int EPI>
static __device__ __forceinline__ void gemm_engine(
    const unsigned short* __restrict__ A0, int lda0, int K0,
    const unsigned short* __restrict__ A1, int lda1,
    const unsigned short* __restrict__ BT, int ldb,
    unsigned short* __restrict__ C0, int ldc,
    unsigned short* __restrict__ C1,
    const float* __restrict__ bias,
    const float* __restrict__ base_tau,
    int mb, int nb, int K,
    unsigned short* As, unsigned short* Bs)
{
  const int tid = threadIdx.x;
  const int lane = tid & 63;
  const int wid = tid >> 6;
  const int wm = (wid >> 1) * 64;
  const int wn = (wid & 1) * 64;
  const int srow = lane >> 2;          // staging row within 16-row chunk
  const int scol = (lane & 3) * 8;     // staging col (elements)
  const int fr = lane & 15;            // fragment row/col
  const int fk = (lane >> 4) * 8;      // fragment k-octet
  const int NT = K / 32;               // NT >= 2 always here

  f32x4 acc[4][4];
#pragma unroll
  for (int i = 0; i < 4; i++)
#pragma unroll
    for (int j = 0; j < 4; j++)
      acc[i][j] = (f32x4){ 0.f, 0.f, 0.f, 0.f };

  // stage tile t into buffer buf (4 gload_lds per thread-wave: 2 A + 2 B)
  auto STAGE = [&](int buf, int t) {
    const int k0 = t * 32;
    const bool s0 = (k0 < K0);
    const unsigned short* Ab = s0 ? A0 : A1;
    const int ld = s0 ? lda0 : lda1;
    const int ko = (s0 ? k0 : k0 - K0) + scol;
    unsigned short* ab = As + buf * 4096 + (32 * wid) * 32;
    unsigned short* bb = Bs + buf * 4096 + (32 * wid) * 32;
#pragma unroll
    for (int c = 0; c < 2; c++) {
      const int r = 32 * wid + c * 16 + srow;
      gl_lds16(Ab + (size_t)(mb + r) * ld + ko, ab + c * 16 * 32);
      gl_lds16(BT + (size_t)(nb + r) * ldb + k0 + scol, bb + c * 16 * 32);
    }
  };

  STAGE(0, 0);
  STAGE(1, 1);
  asm volatile("s_waitcnt vmcnt(4)" ::: "memory");  // tile 0 landed, tile 1 in flight
  __builtin_amdgcn_s_barrier();

  int cur = 0, stg = 2;
  for (int t = 0; t < NT; t++) {
    if (t + 2 < NT) STAGE(stg, t + 2);

    const unsigned short* ar = As + cur * 4096;
    const unsigned short* br = Bs + cur * 4096;
    s16x8 af[4], bv[4];
#pragma unroll
    for (int mi = 0; mi < 4; mi++)
      af[mi] = *(const s16x8*)(ar + (wm + mi * 16 + fr) * 32 + fk);
#pragma unroll
    for (int ni = 0; ni < 4; ni++)
      bv[ni] = *(const s16x8*)(br + (wn + ni * 16 + fr) * 32 + fk);

    // all ds_reads complete before this wave's barrier (buffer-reuse safety),
    // and MFMAs pinned after the wait (rule #18).
    asm volatile("s_waitcnt lgkmcnt(0)" ::: "memory");
    __builtin_amdgcn_sched_barrier(0);

#pragma unroll
    for (int mi = 0; mi < 4; mi++)
#pragma unroll
      for (int ni = 0; ni < 4; ni++)
        acc[mi][ni] = __builtin_amdgcn_mfma_f32_16x16x32_bf16(
            af[mi], bv[ni], acc[mi][ni], 0, 0, 0);

    if (t + 1 < NT) {
      if (t + 2 < NT) asm volatile("s_waitcnt vmcnt(4)" ::: "memory");  // t+1 landed
      else            asm volatile("s_waitcnt vmcnt(0)" ::: "memory");  // last in flight
      __builtin_amdgcn_s_barrier();
    }
    cur = (cur == 2) ? 0 : cur + 1;
    stg = (stg == 2) ? 0 : stg + 1;
  }

  const int rb = (lane >> 4) * 4;
#pragma unroll
  for (int mi = 0; mi < 4; mi++) {
#pragma unroll
    for (int ni = 0; ni < 4; ni++) {
#pragma unroll
      for (int r = 0; r < 4; r++) {
        const int row = mb + wm + mi * 16 + rb + r;
        const int col = nb + wn + ni * 16 + fr;
        float v = acc[mi][ni][r];
        if (EPI == 3) {
          if (col < DH) C0[(size_t)row * DH + col] = f2bf(v + bias[col]);
          else          C1[(size_t)row * DH + (col - DH)] = f2bf(v);
        } else if (EPI == 2) {
          C0[(size_t)row * ldc + col] = f2bf(v);
        } else if (EPI == 1) {
          v += bias[col];
          if ((col >> 9) == 0) {
            const float s = 1.0f / (1.0f + expf(-v));
            v = 1.0f / (base_tau[col & (DH - 1)] * 2.0f * s + 1e-8f);  // tau_inv
          } else {
            v = 1.0f + 0.5f * tanhf(v);                                 // A_row/B_col
          }
          C0[(size_t)row * ldc + col] = f2bf(v);
        }
      }
    }
  }
}

// ---- fused G1|GB: [x|h] @ [W1 | base_B~] -> pre1, rawB. XCD-swizzled. ----
__global__ __launch_bounds__(256) void fused_gemm_k(
    const unsigned short* __restrict__ xbf,
    const unsigned short* __restrict__ hbf,
    const unsigned short* __restrict__ BTcat,
    unsigned short* __restrict__ pre1,
    unsigned short* __restrict__ rawB,
    const float* __restrict__ b1)
{
  __shared__ unsigned short As[3 * 4096];
  __shared__ unsigned short Bs[3 * 4096];
  const int cpx = gridDim.x >> 3;                             // 512/8 = 64
  const int virt = (blockIdx.x & 7) * cpx + (blockIdx.x >> 3);
  const int mb = (virt & 63) * 128;
  const int nb = (virt >> 6) * 128;
  gemm_engine<3>(xbf, DIN, DIN, hbf, DH, BTcat, DIN + DH,
                 pre1, DH, rawB, b1, nullptr, mb, nb, DIN + DH, As, Bs);
}

// ---- merged tail: blocks [0,768) G2 scales; [768,1024) GA rawA ----
__global__ __launch_bounds__(256) void tail_gemm_k(
    const unsigned short* __restrict__ hbf,
    const unsigned short* __restrict__ Abf,
    const unsigned short* __restrict__ tbf,
    const unsigned short* __restrict__ W2T,
    unsigned short* __restrict__ rawA,
    unsigned short* __restrict__ scales,
    const float* __restrict__ b2,
    const float* __restrict__ base_tau)
{
  __shared__ unsigned short As[3 * 4096];
  __shared__ unsigned short Bs[3 * 4096];
  const int b = blockIdx.x;
  if (b < 768) {
    const int mb = (b & 63) * 128, nb = (b >> 6) * 128;   // N = 12*128 = 1536
    gemm_engine<1>(tbf, DH, DH, nullptr, 0, W2T, DH,
                   scales, 3 * DH, nullptr, b2, base_tau, mb, nb, DH, As, Bs);
  } else {
    const int b2i = b - 768;
    const int mb = (b2i & 63) * 128, nb = (b2i >> 6) * 128;  // N = 4*128 = 512
    gemm_engine<2>(hbf, DH, DH, nullptr, 0, Abf, DH,
                   rawA, DH, nullptr, nullptr, nullptr, mb, nb, DH, As, Bs);
  }
}

// ---------- block-wide sum over 256 threads (4 waves) ----------
__device__ __forceinline__ float block_sum256(float v, float* red) {
#pragma unroll
  for (int m = 32; m >= 1; m >>= 1) v += __shfl_xor(v, m, 64);
  __syncthreads();
  if ((threadIdx.x & 63) == 0) red[threadIdx.x >> 6] = v;
  __syncthreads();
  return red[0] + red[1] + red[2] + red[3];
}

// ---------- t = bf16(gelu_exact(LN(pre1))) ----------
__global__ __launch_bounds__(256) void ln_gelu_k(
    const unsigned short* __restrict__ pre,
    const float* __restrict__ g, const float* __restrict__ b,
    unsigned short* __restrict__ t)
{
  __shared__ float red[4];
  const int row = blockIdx.x;
  const int c = threadIdx.x * 2;
  const size_t ro = (size_t)row * DH;
  u16x2 raw = *(const u16x2*)(pre + ro + c);
  const float v0 = bf2f(raw[0]), v1 = bf2f(raw[1]);
  const float mu = block_sum256(v0 + v1, red) * (1.0f / DH);
  const float d0 = v0 - mu, d1 = v1 - mu;
  const float var = block_sum256(d0 * d0 + d1 * d1, red) * (1.0f / DH);
  const float inv = rsqrtf(var + 1e-5f);
  const float y0 = d0 * inv * g[c] + b[c];
  const float y1 = d1 * inv * g[c + 1] + b[c + 1];
  u16x2 o = { f2bf(0.5f * y0 * (1.0f + erff(y0 * 0.70710678118f))),
              f2bf(0.5f * y1 * (1.0f + erff(y1 * 0.70710678118f))) };
  *(u16x2*)(t + ro + c) = o;
}

// ---------- new_h = LN(h + dt*(-h*tauinv + tanh(rawA*arow + rawB*bcol))) ----------
__global__ __launch_bounds__(256) void final_k(
    const float* __restrict__ h,
    const unsigned short* __restrict__ rawA,
    const unsigned short* __restrict__ rawB,
    const unsigned short* __restrict__ scales,
    const float* __restrict__ hn_g, const float* __restrict__ hn_b,
    float* __restrict__ out)
{
  __shared__ float red[4];
  const int row = blockIdx.x;
  const int c = threadIdx.x * 2;
  const size_t ro = (size_t)row * DH;
  f32x2 hv = *(const f32x2*)(h + ro + c);
  u16x2 ra = *(const u16x2*)(rawA + ro + c);
  u16x2 rb = *(const u16x2*)(rawB + ro + c);
  const unsigned short* sc = scales + (size_t)row * (3 * DH);
  u16x2 ti  = *(const u16x2*)(sc + c);
  u16x2 arw = *(const u16x2*)(sc + DH + c);
  u16x2 bcl = *(const u16x2*)(sc + 2 * DH + c);
  const float u0 = hv[0] + 0.1f * (-hv[0] * bf2f(ti[0])
                 + tanhf(bf2f(ra[0]) * bf2f(arw[0]) + bf2f(rb[0]) * bf2f(bcl[0])));
  const float u1 = hv[1] + 0.1f * (-hv[1] * bf2f(ti[1])
                 + tanhf(bf2f(ra[1]) * bf2f(arw[1]) + bf2f(rb[1]) * bf2f(bcl[1])));
  const float mu = block_sum256(u0 + u1, red) * (1.0f / DH);
  const float d0 = u0 - mu, d1 = u1 - mu;
  const float var = block_sum256(d0 * d0 + d1 * d1, red) * (1.0f / DH);
  const float inv = rsqrtf(var + 1e-5f);
  f32x2 o = { d0 * inv * hn_g[c] + hn_b[c],
              d1 * inv * hn_g[c + 1] + hn_b[c + 1] };
  *(f32x2*)(out + ro + c) = o;
}

extern "C" void kernel_launch(void* const* d_in, const int* in_sizes, int n_in,
                              void* d_out, int out_size, void* d_ws, size_t ws_size,
                              hipStream_t stream)
{
  const float* x        = (const float*)d_in[0];
  const float* h        = (const float*)d_in[1];
  const float* W1       = (const float*)d_in[2];   // [4608][512]
  const float* b1       = (const float*)d_in[3];
  const float* ln1_g    = (const float*)d_in[4];
  const float* ln1_b    = (const float*)d_in[5];
  const float* W2       = (const float*)d_in[6];   // [512][1536]
  const float* b2       = (const float*)d_in[7];
  const float* base_tau = (const float*)d_in[8];
  const float* base_A   = (const float*)d_in[9];   // [512][512]
  const float* base_B   = (const float*)d_in[10];  // [4096][512]
  const float* hn_g     = (const float*)d_in[11];
  const float* hn_b     = (const float*)d_in[12];

  const int KC = DIN + DH;  // 4608
  char* w = (char*)d_ws;
  // ws layout (bytes), total 128,974,848 (== proven-safe footprint):
  unsigned short* xbf    = (unsigned short*)(w);               // [8192][4096] 67,108,864
  unsigned short* hbf    = (unsigned short*)(w + 67108864);    // [8192][512]   8,388,608
  unsigned short* BTcat  = (unsigned short*)(w + 75497472);    // [1024][4608]  9,437,184
  unsigned short* tbf    = (unsigned short*)(w + 75497472);    // ALIAS over BTcat (dead after fused GEMM)
  unsigned short* W2T    = (unsigned short*)(w + 84934656);    // [1536][512]   1,572,864
  unsigned short* Abf    = (unsigned short*)(w + 86507520);    // [512][512]      524,288
  unsigned short* pre1   = (unsigned short*)(w + 87031808);    // [8192][512]   8,388,608
  unsigned short* rawA   = (unsigned short*)(w + 87031808);    // ALIAS over pre1 (dead after ln_gelu)
  unsigned short* rawB   = (unsigned short*)(w + 95420416);    // [8192][512]   8,388,608
  unsigned short* scales = (unsigned short*)(w + 103809024);   // [8192][1536] 25,165,824

  // ---- prep: casts + weight transposes ----
  cast_bf16_k<<<DIN * BATCH / 1024, 256, 0, stream>>>(x, xbf);
  cast_bf16_k<<<DH * BATCH / 1024, 256, 0, stream>>>(h, hbf);
  cast_bf16_k<<<DH * DH / 1024, 256, 0, stream>>>(base_A, Abf);
  dim3 tb(32, 8);
  transpose_bf16_k<<<dim3(DH / 32, KC / 32), tb, 0, stream>>>(W1, KC, DH, BTcat, KC, 0);
  transpose_bf16_k<<<dim3(DH / 32, DIN / 32), tb, 0, stream>>>(base_B, DIN, DH, BTcat, KC, DH);
  zfill_k<<<128, 256, 0, stream>>>(BTcat + (size_t)DH * KC + DIN, KC, DH, DH / 8);
  transpose_bf16_k<<<dim3(3 * DH / 32, DH / 32), tb, 0, stream>>>(W2, DH, 3 * DH, W2T, DH, 0);

  // ---- fused G1|GB -> pre1, rawB ----
  fused_gemm_k<<<512, 256, 0, stream>>>(xbf, hbf, BTcat, pre1, rawB, b1);
  // ---- t = gelu(LN(pre1)) -> tbf ----
  ln_gelu_k<<<BATCH, 256, 0, stream>>>(pre1, ln1_g, ln1_b, tbf);
  // ---- merged tail: scales = transforms(t @ W2 + b2); rawA = h @ base_A^T ----
  tail_gemm_k<<<1024, 256, 0, stream>>>(hbf, Abf, tbf, W2T, rawA, scales, b2, base_tau);
  // ---- final: dhdt + LN -> f32 out ----
  final_k<<<BATCH, 256, 0, stream>>>(h, rawA, rawB, scales, hn_g, hn_b, (float*)d_out);
}

// Round 6
// 236.266 us; speedup vs baseline: 1.2864x; 1.0244x over previous
//
#include <hip/hip_runtime.h>

#define BATCH 8192
#define DIN 4096
#define DH 512

typedef float f32x4 __attribute__((ext_vector_type(4)));
typedef float f32x2 __attribute__((ext_vector_type(2)));
typedef short s16x8 __attribute__((ext_vector_type(8)));
typedef unsigned short u16x2 __attribute__((ext_vector_type(2)));
typedef unsigned short u16x4 __attribute__((ext_vector_type(4)));
typedef unsigned short u16x8 __attribute__((ext_vector_type(8)));

// round-to-nearest-even f32 -> bf16 bits
static __device__ __forceinline__ unsigned short f2bf(float f) {
  unsigned int u = __float_as_uint(f);
  u += 0x7FFFu + ((u >> 16) & 1u);
  return (unsigned short)(u >> 16);
}
static __device__ __forceinline__ float bf2f(unsigned short s) {
  return __uint_as_float(((unsigned int)s) << 16);
}

typedef const __attribute__((address_space(1))) unsigned int* gas_ptr;
typedef __attribute__((address_space(3))) unsigned int* las_ptr;
// async global->LDS, 16B per lane; LDS dest = uniform base + lane*16
static __device__ __forceinline__ void gl_lds16(const unsigned short* g, unsigned short* l) {
  __builtin_amdgcn_global_load_lds((gas_ptr)g, (las_ptr)l, 16, 0, 0);
}

// ---------- elementwise f32 -> bf16 (big arrays; x) ----------
__global__ __launch_bounds__(256) void cast_bf16_k(
    const float* __restrict__ in, unsigned short* __restrict__ out)
{
  const int i = (blockIdx.x * 256 + threadIdx.x) * 4;
  f32x4 v = *(const f32x4*)(in + i);
  u16x4 p = { f2bf(v[0]), f2bf(v[1]), f2bf(v[2]), f2bf(v[3]) };
  *(u16x4*)(out + i) = p;
}

// ---------- transpose tile body: in f32 [R][C] -> out bf16 [(row_off+c)][r] ----------
static __device__ __forceinline__ void transpose_body(
    const float* __restrict__ in, int C,
    unsigned short* __restrict__ out, int ldo, int row_off,
    int bx, int by, float (*tl)[33])
{
  const int tid = threadIdx.x;
  const int tx = tid & 31, ty = tid >> 5;
  const int c0 = bx * 32, r0 = by * 32;
#pragma unroll
  for (int i = 0; i < 4; i++)
    tl[ty + 8 * i][tx] = in[(size_t)(r0 + ty + 8 * i) * C + c0 + tx];
  __syncthreads();
#pragma unroll
  for (int i = 0; i < 4; i++)
    out[(size_t)(row_off + c0 + ty + 8 * i) * ldo + r0 + tx] = f2bf(tl[tx][ty + 8 * i]);
}

// ---------- merged small prep: cast_h | cast_A | T(W1) | T(base_B) | zfill | T(W2) ----------
// block ranges: [0,4096) cast h; [4096,4352) cast A; [4352,6656) T W1;
// [6656,8704) T base_B; [8704,8832) zfill; [8832,9600) T W2.
__global__ __launch_bounds__(256) void prep_small_k(
    const float* __restrict__ h, unsigned short* __restrict__ hbf,
    const float* __restrict__ base_A, unsigned short* __restrict__ Abf,
    const float* __restrict__ W1, const float* __restrict__ base_B,
    unsigned short* __restrict__ BTcat,
    const float* __restrict__ W2, unsigned short* __restrict__ W2T)
{
  __shared__ float tl[32][33];
  const int b = blockIdx.x;
  const int tid = threadIdx.x;
  const int KC = DIN + DH;
  if (b < 4096) {
    const int i = (b * 256 + tid) * 4;
    f32x4 v = *(const f32x4*)(h + i);
    u16x4 p = { f2bf(v[0]), f2bf(v[1]), f2bf(v[2]), f2bf(v[3]) };
    *(u16x4*)(hbf + i) = p;
  } else if (b < 4352) {
    const int i = ((b - 4096) * 256 + tid) * 4;
    f32x4 v = *(const f32x4*)(base_A + i);
    u16x4 p = { f2bf(v[0]), f2bf(v[1]), f2bf(v[2]), f2bf(v[3]) };
    *(u16x4*)(Abf + i) = p;
  } else if (b < 6656) {
    const int bb = b - 4352;                       // W1 [4608][512]
    transpose_body(W1, DH, BTcat, KC, 0, bb & 15, bb >> 4, tl);
  } else if (b < 8704) {
    const int bb = b - 6656;                       // base_B [4096][512]
    transpose_body(base_B, DH, BTcat, KC, DH, bb & 15, bb >> 4, tl);
  } else if (b < 8832) {
    const int gid = (b - 8704) * 256 + tid;        // zero pad corner 512x512
    const int row = gid >> 6, c = (gid & 63) * 8;
    u16x8 z = { 0, 0, 0, 0, 0, 0, 0, 0 };
    *(u16x8*)(BTcat + (size_t)(DH + row) * KC + DIN + c) = z;
  } else {
    const int bb = b - 8832;                       // W2 [512][1536]
    transpose_body(W2, 3 * DH, W2T, DH, 0, bb % 48, bb / 48, tl);
  }
}

// ---------------------------------------------------------------------------
// Pipelined GEMM engine (T3/T4): 128x128 tile, BK=32, DEPTH-deep LDS pipeline,
// counted vmcnt (steady-state 4*(DEPTH-2), never 0 in main loop), raw barrier.
// A,BT bf16. 4 waves (2x2, 64x64 each, 4x4 frags of 16x16x32), gload_lds.
// EPI: 1 = +bias then scale transforms -> C0; 2 = raw -> C0;
//      3 = split: col<512 -> C0 +bias ; col>=512 -> C1 raw (both ld 512).
// Requires NT >= DEPTH-1.
// ---------------------------------------------------------------------------
template<int EPI, int DEPTH>
static __device__ __forceinline__ void gemm_engine(
    const unsigned short* __restrict__ A0, int lda0, int K0,
    const unsigned short* __restrict__ A1, int lda1,
    const unsigned short* __restrict__ BT, int ldb,
    unsigned short* __restrict__ C0, int ldc,
    unsigned short* __restrict__ C1,
    const float* __restrict__ bias,
    const float* __restrict__ base_tau,
    int mb, int nb, int K,
    unsigned short* As, unsigned short* Bs)
{
  const int tid = threadIdx.x;
  const int lane = tid & 63;
  const int wid = tid >> 6;
  const int wm = (wid >> 1) * 64;
  const int wn = (wid & 1) * 64;
  const int srow = lane >> 2;          // staging row within 16-row chunk
  const int scol = (lane & 3) * 8;     // staging col (elements)
  const int fr = lane & 15;            // fragment row/col
  const int fk = (lane >> 4) * 8;      // fragment k-octet
  const int NT = K / 32;

  f32x4 acc[4][4];
#pragma unroll
  for (int i = 0; i < 4; i++)
#pragma unroll
    for (int j = 0; j < 4; j++)
      acc[i][j] = (f32x4){ 0.f, 0.f, 0.f, 0.f };

  // stage tile t into buffer buf (4 gl_lds per thread: 2 A + 2 B)
  auto STAGE = [&](int buf, int t) {
    const int k0 = t * 32;
    const bool s0 = (k0 < K0);
    const unsigned short* Ab = s0 ? A0 : A1;
    const int ld = s0 ? lda0 : lda1;
    const int ko = (s0 ? k0 : k0 - K0) + scol;
    unsigned short* ab = As + buf * 4096 + (32 * wid) * 32;
    unsigned short* bb = Bs + buf * 4096 + (32 * wid) * 32;
#pragma unroll
    for (int c = 0; c < 2; c++) {
      const int r = 32 * wid + c * 16 + srow;
      gl_lds16(Ab + (size_t)(mb + r) * ld + ko, ab + c * 16 * 32);
      gl_lds16(BT + (size_t)(nb + r) * ldb + k0 + scol, bb + c * 16 * 32);
    }
  };

  // prologue: stage DEPTH-1 tiles; wait for tile 0
#pragma unroll
  for (int d = 0; d < DEPTH - 1; d++) STAGE(d, d);
  if (DEPTH == 4) asm volatile("s_waitcnt vmcnt(8)" ::: "memory");
  else            asm volatile("s_waitcnt vmcnt(4)" ::: "memory");
  __builtin_amdgcn_s_barrier();

  for (int t = 0; t < NT; t++) {
    if (t + DEPTH - 1 < NT) STAGE((t + DEPTH - 1) % DEPTH, t + DEPTH - 1);

    const unsigned short* ar = As + (t % DEPTH) * 4096;
    const unsigned short* br = Bs + (t % DEPTH) * 4096;
    s16x8 af[4], bv[4];
#pragma unroll
    for (int mi = 0; mi < 4; mi++)
      af[mi] = *(const s16x8*)(ar + (wm + mi * 16 + fr) * 32 + fk);
#pragma unroll
    for (int ni = 0; ni < 4; ni++)
      bv[ni] = *(const s16x8*)(br + (wn + ni * 16 + fr) * 32 + fk);

    // reads complete before this wave's barrier (buffer-reuse safety),
    // MFMAs pinned after the wait (rule #18).
    asm volatile("s_waitcnt lgkmcnt(0)" ::: "memory");
    __builtin_amdgcn_sched_barrier(0);

#pragma unroll
    for (int mi = 0; mi < 4; mi++)
#pragma unroll
      for (int ni = 0; ni < 4; ni++)
        acc[mi][ni] = __builtin_amdgcn_mfma_f32_16x16x32_bf16(
            af[mi], bv[ni], acc[mi][ni], 0, 0, 0);

    if (t + 1 < NT) {
      const int rem = NT - 2 - t;                       // tiles in flight past t+1
      const int nw = (rem < DEPTH - 2) ? rem : DEPTH - 2;
      if (nw >= 2)      asm volatile("s_waitcnt vmcnt(8)" ::: "memory");
      else if (nw == 1) asm volatile("s_waitcnt vmcnt(4)" ::: "memory");
      else              asm volatile("s_waitcnt vmcnt(0)" ::: "memory");
      __builtin_amdgcn_s_barrier();
    }
  }

  const int rb = (lane >> 4) * 4;
#pragma unroll
  for (int mi = 0; mi < 4; mi++) {
#pragma unroll
    for (int ni = 0; ni < 4; ni++) {
#pragma unroll
      for (int r = 0; r < 4; r++) {
        const int row = mb + wm + mi * 16 + rb + r;
        const int col = nb + wn + ni * 16 + fr;
        float v = acc[mi][ni][r];
        if (EPI == 3) {
          if (col < DH) C0[(size_t)row * DH + col] = f2bf(v + bias[col]);
          else          C1[(size_t)row * DH + (col - DH)] = f2bf(v);
        } else if (EPI == 2) {
          C0[(size_t)row * ldc + col] = f2bf(v);
        } else if (EPI == 1) {
          v += bias[col];
          if ((col >> 9) == 0) {
            const float s = 1.0f / (1.0f + expf(-v));
            v = 1.0f / (base_tau[col & (DH - 1)] * 2.0f * s + 1e-8f);  // tau_inv
          } else {
            v = 1.0f + 0.5f * tanhf(v);                                 // A_row/B_col
          }
          C0[(size_t)row * ldc + col] = f2bf(v);
        }
      }
    }
  }
}

// ---- fused G1|GB: [x|h] @ [W1 | base_B~] -> pre1, rawB. XCD-swizzled, 4-deep ----
__global__ __launch_bounds__(256) void fused_gemm_k(
    const unsigned short* __restrict__ xbf,
    const unsigned short* __restrict__ hbf,
    const unsigned short* __restrict__ BTcat,
    unsigned short* __restrict__ pre1,
    unsigned short* __restrict__ rawB,
    const float* __restrict__ b1)
{
  __shared__ unsigned short As[4 * 4096];
  __shared__ unsigned short Bs[4 * 4096];
  const int cpx = gridDim.x >> 3;                             // 512/8 = 64
  const int virt = (blockIdx.x & 7) * cpx + (blockIdx.x >> 3);
  const int mb = (virt & 63) * 128;
  const int nb = (virt >> 6) * 128;
  gemm_engine<3, 4>(xbf, DIN, DIN, hbf, DH, BTcat, DIN + DH,
                    pre1, DH, rawB, b1, nullptr, mb, nb, DIN + DH, As, Bs);
}

// ---- merged tail: blocks [0,768) G2 scales; [768,1024) GA rawA. 3-deep ----
__global__ __launch_bounds__(256) void tail_gemm_k(
    const unsigned short* __restrict__ hbf,
    const unsigned short* __restrict__ Abf,
    const unsigned short* __restrict__ tbf,
    const unsigned short* __restrict__ W2T,
    unsigned short* __restrict__ rawA,
    unsigned short* __restrict__ scales,
    const float* __restrict__ b2,
    const float* __restrict__ base_tau)
{
  __shared__ unsigned short As[3 * 4096];
  __shared__ unsigned short Bs[3 * 4096];
  const int b = blockIdx.x;
  if (b < 768) {
    const int mb = (b & 63) * 128, nb = (b >> 6) * 128;   // N = 12*128 = 1536
    gemm_engine<1, 3>(tbf, DH, DH, nullptr, 0, W2T, DH,
                      scales, 3 * DH, nullptr, b2, base_tau, mb, nb, DH, As, Bs);
  } else {
    const int b2i = b - 768;
    const int mb = (b2i & 63) * 128, nb = (b2i >> 6) * 128;  // N = 4*128 = 512
    gemm_engine<2, 3>(hbf, DH, DH, nullptr, 0, Abf, DH,
                      rawA, DH, nullptr, nullptr, nullptr, mb, nb, DH, As, Bs);
  }
}

// ---------- block-wide sum over 256 threads (4 waves) ----------
__device__ __forceinline__ float block_sum256(float v, float* red) {
#pragma unroll
  for (int m = 32; m >= 1; m >>= 1) v += __shfl_xor(v, m, 64);
  __syncthreads();
  if ((threadIdx.x & 63) == 0) red[threadIdx.x >> 6] = v;
  __syncthreads();
  return red[0] + red[1] + red[2] + red[3];
}

// ---------- t = bf16(gelu_exact(LN(pre1))) ----------
__global__ __launch_bounds__(256) void ln_gelu_k(
    const unsigned short* __restrict__ pre,
    const float* __restrict__ g, const float* __restrict__ b,
    unsigned short* __restrict__ t)
{
  __shared__ float red[4];
  const int row = blockIdx.x;
  const int c = threadIdx.x * 2;
  const size_t ro = (size_t)row * DH;
  u16x2 raw = *(const u16x2*)(pre + ro + c);
  const float v0 = bf2f(raw[0]), v1 = bf2f(raw[1]);
  const float mu = block_sum256(v0 + v1, red) * (1.0f / DH);
  const float d0 = v0 - mu, d1 = v1 - mu;
  const float var = block_sum256(d0 * d0 + d1 * d1, red) * (1.0f / DH);
  const float inv = rsqrtf(var + 1e-5f);
  const float y0 = d0 * inv * g[c] + b[c];
  const float y1 = d1 * inv * g[c + 1] + b[c + 1];
  u16x2 o = { f2bf(0.5f * y0 * (1.0f + erff(y0 * 0.70710678118f))),
              f2bf(0.5f * y1 * (1.0f + erff(y1 * 0.70710678118f))) };
  *(u16x2*)(t + ro + c) = o;
}

// ---------- new_h = LN(h + dt*(-h*tauinv + tanh(rawA*arow + rawB*bcol))) ----------
__global__ __launch_bounds__(256) void final_k(
    const float* __restrict__ h,
    const unsigned short* __restrict__ rawA,
    const unsigned short* __restrict__ rawB,
    const unsigned short* __restrict__ scales,
    const float* __restrict__ hn_g, const float* __restrict__ hn_b,
    float* __restrict__ out)
{
  __shared__ float red[4];
  const int row = blockIdx.x;
  const int c = threadIdx.x * 2;
  const size_t ro = (size_t)row * DH;
  f32x2 hv = *(const f32x2*)(h + ro + c);
  u16x2 ra = *(const u16x2*)(rawA + ro + c);
  u16x2 rb = *(const u16x2*)(rawB + ro + c);
  const unsigned short* sc = scales + (size_t)row * (3 * DH);
  u16x2 ti  = *(const u16x2*)(sc + c);
  u16x2 arw = *(const u16x2*)(sc + DH + c);
  u16x2 bcl = *(const u16x2*)(sc + 2 * DH + c);
  const float u0 = hv[0] + 0.1f * (-hv[0] * bf2f(ti[0])
                 + tanhf(bf2f(ra[0]) * bf2f(arw[0]) + bf2f(rb[0]) * bf2f(bcl[0])));
  const float u1 = hv[1] + 0.1f * (-hv[1] * bf2f(ti[1])
                 + tanhf(bf2f(ra[1]) * bf2f(arw[1]) + bf2f(rb[1]) * bf2f(bcl[1])));
  const float mu = block_sum256(u0 + u1, red) * (1.0f / DH);
  const float d0 = u0 - mu, d1 = u1 - mu;
  const float var = block_sum256(d0 * d0 + d1 * d1, red) * (1.0f / DH);
  const float inv = rsqrtf(var + 1e-5f);
  f32x2 o = { d0 * inv * hn_g[c] + hn_b[c],
              d1 * inv * hn_g[c + 1] + hn_b[c + 1] };
  *(f32x2*)(out + ro + c) = o;
}

extern "C" void kernel_launch(void* const* d_in, const int* in_sizes, int n_in,
                              void* d_out, int out_size, void* d_ws, size_t ws_size,
                              hipStream_t stream)
{
  const float* x        = (const float*)d_in[0];
  const float* h        = (const float*)d_in[1];
  const float* W1       = (const float*)d_in[2];   // [4608][512]
  const float* b1       = (const float*)d_in[3];
  const float* ln1_g    = (const float*)d_in[4];
  const float* ln1_b    = (const float*)d_in[5];
  const float* W2       = (const float*)d_in[6];   // [512][1536]
  const float* b2       = (const float*)d_in[7];
  const float* base_tau = (const float*)d_in[8];
  const float* base_A   = (const float*)d_in[9];   // [512][512]
  const float* base_B   = (const float*)d_in[10];  // [4096][512]
  const float* hn_g     = (const float*)d_in[11];
  const float* hn_b     = (const float*)d_in[12];

  char* w = (char*)d_ws;
  // ws layout (bytes), total 128,974,848 (== proven-safe footprint):
  unsigned short* xbf    = (unsigned short*)(w);               // [8192][4096] 67,108,864
  unsigned short* hbf    = (unsigned short*)(w + 67108864);    // [8192][512]   8,388,608
  unsigned short* BTcat  = (unsigned short*)(w + 75497472);    // [1024][4608]  9,437,184
  unsigned short* tbf    = (unsigned short*)(w + 75497472);    // ALIAS over BTcat (dead after fused GEMM)
  unsigned short* W2T    = (unsigned short*)(w + 84934656);    // [1536][512]   1,572,864
  unsigned short* Abf    = (unsigned short*)(w + 86507520);    // [512][512]      524,288
  unsigned short* pre1   = (unsigned short*)(w + 87031808);    // [8192][512]   8,388,608
  unsigned short* rawA   = (unsigned short*)(w + 87031808);    // ALIAS over pre1 (dead after ln_gelu)
  unsigned short* rawB   = (unsigned short*)(w + 95420416);    // [8192][512]   8,388,608
  unsigned short* scales = (unsigned short*)(w + 103809024);   // [8192][1536] 25,165,824

  // ---- prep: big x cast + merged small prep ----
  cast_bf16_k<<<DIN * BATCH / 1024, 256, 0, stream>>>(x, xbf);
  prep_small_k<<<9600, 256, 0, stream>>>(h, hbf, base_A, Abf, W1, base_B, BTcat, W2, W2T);

  // ---- fused G1|GB -> pre1, rawB ----
  fused_gemm_k<<<512, 256, 0, stream>>>(xbf, hbf, BTcat, pre1, rawB, b1);
  // ---- t = gelu(LN(pre1)) -> tbf ----
  ln_gelu_k<<<BATCH, 256, 0, stream>>>(pre1, ln1_g, ln1_b, tbf);
  // ---- merged tail: scales = transforms(t @ W2 + b2); rawA = h @ base_A^T ----
  tail_gemm_k<<<1024, 256, 0, stream>>>(hbf, Abf, tbf, W2T, rawA, scales, b2, base_tau);
  // ---- final: dhdt + LN -> f32 out ----
  final_k<<<BATCH, 256, 0, stream>>>(h, rawA, rawB, scales, hn_g, hn_b, (float*)d_out);
}

// Round 7
// 219.620 us; speedup vs baseline: 1.3839x; 1.0758x over previous
//
#include <hip/hip_runtime.h>

#define BATCH 8192
#define DIN 4096
#define DH 512

typedef float f32x4 __attribute__((ext_vector_type(4)));
typedef float f32x2 __attribute__((ext_vector_type(2)));
typedef short s16x8 __attribute__((ext_vector_type(8)));
typedef unsigned short u16x2 __attribute__((ext_vector_type(2)));
typedef unsigned short u16x4 __attribute__((ext_vector_type(4)));
typedef unsigned short u16x8 __attribute__((ext_vector_type(8)));

// round-to-nearest-even f32 -> bf16 bits
static __device__ __forceinline__ unsigned short f2bf(float f) {
  unsigned int u = __float_as_uint(f);
  u += 0x7FFFu + ((u >> 16) & 1u);
  return (unsigned short)(u >> 16);
}
static __device__ __forceinline__ float bf2f(unsigned short s) {
  return __uint_as_float(((unsigned int)s) << 16);
}

typedef const __attribute__((address_space(1))) unsigned int* gas_ptr;
typedef __attribute__((address_space(3))) unsigned int* las_ptr;
// async global->LDS, 16B per lane; LDS dest = wave-uniform base + lane*16
static __device__ __forceinline__ void gl_lds16(const unsigned short* g, unsigned short* l) {
  __builtin_amdgcn_global_load_lds((gas_ptr)g, (las_ptr)l, 16, 0, 0);
}

// ---------- elementwise f32 -> bf16 (big arrays; x) ----------
__global__ __launch_bounds__(256) void cast_bf16_k(
    const float* __restrict__ in, unsigned short* __restrict__ out)
{
  const int i = (blockIdx.x * 256 + threadIdx.x) * 4;
  f32x4 v = *(const f32x4*)(in + i);
  u16x4 p = { f2bf(v[0]), f2bf(v[1]), f2bf(v[2]), f2bf(v[3]) };
  *(u16x4*)(out + i) = p;
}

// ---------- transpose tile body: in f32 [R][C] -> out bf16 [(row_off+c)][r] ----------
static __device__ __forceinline__ void transpose_body(
    const float* __restrict__ in, int C,
    unsigned short* __restrict__ out, int ldo, int row_off,
    int bx, int by, float (*tl)[33])
{
  const int tid = threadIdx.x;
  const int tx = tid & 31, ty = tid >> 5;
  const int c0 = bx * 32, r0 = by * 32;
#pragma unroll
  for (int i = 0; i < 4; i++)
    tl[ty + 8 * i][tx] = in[(size_t)(r0 + ty + 8 * i) * C + c0 + tx];
  __syncthreads();
#pragma unroll
  for (int i = 0; i < 4; i++)
    out[(size_t)(row_off + c0 + ty + 8 * i) * ldo + r0 + tx] = f2bf(tl[tx][ty + 8 * i]);
}

// ---------- merged small prep: cast_h | cast_A | T(W1) | T(base_B) | zfill | T(W2) ----------
__global__ __launch_bounds__(256) void prep_small_k(
    const float* __restrict__ h, unsigned short* __restrict__ hbf,
    const float* __restrict__ base_A, unsigned short* __restrict__ Abf,
    const float* __restrict__ W1, const float* __restrict__ base_B,
    unsigned short* __restrict__ BTcat,
    const float* __restrict__ W2, unsigned short* __restrict__ W2T)
{
  __shared__ float tl[32][33];
  const int b = blockIdx.x;
  const int tid = threadIdx.x;
  const int KC = DIN + DH;
  if (b < 4096) {
    const int i = (b * 256 + tid) * 4;
    f32x4 v = *(const f32x4*)(h + i);
    u16x4 p = { f2bf(v[0]), f2bf(v[1]), f2bf(v[2]), f2bf(v[3]) };
    *(u16x4*)(hbf + i) = p;
  } else if (b < 4352) {
    const int i = ((b - 4096) * 256 + tid) * 4;
    f32x4 v = *(const f32x4*)(base_A + i);
    u16x4 p = { f2bf(v[0]), f2bf(v[1]), f2bf(v[2]), f2bf(v[3]) };
    *(u16x4*)(Abf + i) = p;
  } else if (b < 6656) {
    const int bb = b - 4352;                       // W1 [4608][512]
    transpose_body(W1, DH, BTcat, KC, 0, bb & 15, bb >> 4, tl);
  } else if (b < 8704) {
    const int bb = b - 6656;                       // base_B [4096][512]
    transpose_body(base_B, DH, BTcat, KC, DH, bb & 15, bb >> 4, tl);
  } else if (b < 8832) {
    const int gid = (b - 8704) * 256 + tid;        // zero pad corner 512x512
    const int row = gid >> 6, c = (gid & 63) * 8;
    u16x8 z = { 0, 0, 0, 0, 0, 0, 0, 0 };
    *(u16x8*)(BTcat + (size_t)(DH + row) * KC + DIN + c) = z;
  } else {
    const int bb = b - 8832;                       // W2 [512][1536]
    transpose_body(W2, 3 * DH, W2T, DH, 0, bb % 48, bb / 48, tl);
  }
}

// ---------------------------------------------------------------------------
// Dual-K-stream GEMM engine: 128x128 tile, 512 threads = 8 waves in 2 groups.
// Group g computes K-tiles 2t+g (t = 0..K/64-1); each group's 4 waves own
// 64x64 sub-tiles (4x4 frags of 16x16x32). Per-group double-buffered LDS
// (2x16KB each, 64KB total), 2-phase schedule: STAGE(next) -> ds_read/MFMA ->
// vmcnt(0)+barrier. Bank-conflict swizzle: physical 16B chunk = logical ^
// ((row>>1)&3); on write side this is source-col perm ((l&3)^((l>>3)&3)),
// on read side frag offset ((l>>4)^((l>>1)&3)) — both per-lane constants.
// Epilogue: group 1 dumps f32 accs to LDS, group 0 adds and writes C.
// EPI: 1 = +bias then scale transforms -> C0; 2 = raw -> C0;
//      3 = split: col<512 -> C0 +bias ; col>=512 -> C1 raw (both ld 512).
// ---------------------------------------------------------------------------
template<int EPI>
static __device__ __forceinline__ void gemm2_engine(
    const unsigned short* __restrict__ A0, int lda0, int K0,
    const unsigned short* __restrict__ A1, int lda1,
    const unsigned short* __restrict__ BT, int ldb,
    unsigned short* __restrict__ C0, int ldc,
    unsigned short* __restrict__ C1,
    const float* __restrict__ bias,
    const float* __restrict__ base_tau,
    int mb, int nb, int K, char* smem)
{
  unsigned short* As = (unsigned short*)smem;             // [grp][buf][4096]
  unsigned short* Bs = (unsigned short*)(smem + 32768);   // [grp][buf][4096]
  float* red = (float*)smem;                              // 64KB reduction (reuse)

  const int tid = threadIdx.x;
  const int lane = tid & 63;
  const int wid = tid >> 6;        // 0..7
  const int grp = wid >> 2;        // 0 = even K-tiles, 1 = odd
  const int wg  = wid & 3;         // wave within group
  const int wm = (wg >> 1) * 64;
  const int wn = (wg & 1) * 64;
  const int srow = lane >> 2;                                // staging row in 16-chunk
  const int scol = ((lane & 3) ^ ((lane >> 3) & 3)) * 8;     // swizzled source chunk
  const int fr = lane & 15;                                  // fragment row/col
  const int fk = ((lane >> 4) ^ ((lane >> 1) & 3)) * 8;      // swizzled read chunk
  const int NT2 = K / 64;          // periods (2 K-tiles consumed per period)

  f32x4 acc[4][4];
#pragma unroll
  for (int i = 0; i < 4; i++)
#pragma unroll
    for (int j = 0; j < 4; j++)
      acc[i][j] = (f32x4){ 0.f, 0.f, 0.f, 0.f };

  // stage this group's tile for period 'per' into buffer buf (4 gl_lds/wave)
  auto STAGE = [&](int buf, int per) {
    const int tk = 2 * per + grp;
    const int k0 = tk * 32;
    const bool s0 = (k0 < K0);
    const unsigned short* Ab = s0 ? A0 : A1;
    const int ld = s0 ? lda0 : lda1;
    const int ko = (s0 ? k0 : k0 - K0) + scol;
    unsigned short* ab = As + (grp * 2 + buf) * 4096 + (32 * wg) * 32;
    unsigned short* bb = Bs + (grp * 2 + buf) * 4096 + (32 * wg) * 32;
#pragma unroll
    for (int c = 0; c < 2; c++) {
      const int r = 32 * wg + c * 16 + srow;
      gl_lds16(Ab + (size_t)(mb + r) * ld + ko, ab + c * 16 * 32);
      gl_lds16(BT + (size_t)(nb + r) * ldb + k0 + scol, bb + c * 16 * 32);
    }
  };

  STAGE(0, 0);
  asm volatile("s_waitcnt vmcnt(0)" ::: "memory");
  __builtin_amdgcn_s_barrier();

  int buf = 0;
  for (int t = 0; t < NT2; t++) {
    if (t + 1 < NT2) STAGE(buf ^ 1, t + 1);   // issue next-period loads first

    const unsigned short* ar = As + (grp * 2 + buf) * 4096;
    const unsigned short* br = Bs + (grp * 2 + buf) * 4096;
    s16x8 af[4], bv[4];
#pragma unroll
    for (int mi = 0; mi < 4; mi++)
      af[mi] = *(const s16x8*)(ar + (wm + mi * 16 + fr) * 32 + fk);
#pragma unroll
    for (int ni = 0; ni < 4; ni++)
      bv[ni] = *(const s16x8*)(br + (wn + ni * 16 + fr) * 32 + fk);

    // reads complete before this wave's barrier (buffer-reuse safety),
    // MFMAs pinned after the wait (rule #18).
    asm volatile("s_waitcnt lgkmcnt(0)" ::: "memory");
    __builtin_amdgcn_sched_barrier(0);

#pragma unroll
    for (int mi = 0; mi < 4; mi++)
#pragma unroll
      for (int ni = 0; ni < 4; ni++)
        acc[mi][ni] = __builtin_amdgcn_mfma_f32_16x16x32_bf16(
            af[mi], bv[ni], acc[mi][ni], 0, 0, 0);

    // next-period loads (issued ~full period ago) must land before reuse
    asm volatile("s_waitcnt vmcnt(0)" ::: "memory");
    __builtin_amdgcn_s_barrier();
    buf ^= 1;
  }

  // ---- cross-group reduction: group1 -> LDS, group0 adds ----
  if (grp == 1) {
#pragma unroll
    for (int mi = 0; mi < 4; mi++)
#pragma unroll
      for (int ni = 0; ni < 4; ni++)
        *(f32x4*)(red + (((wg * 4 + mi) * 4 + ni) * 64 + lane) * 4) = acc[mi][ni];
  }
  __syncthreads();
  if (grp != 0) return;

  const int rb = (lane >> 4) * 4;
#pragma unroll
  for (int mi = 0; mi < 4; mi++) {
#pragma unroll
    for (int ni = 0; ni < 4; ni++) {
      f32x4 o = *(const f32x4*)(red + (((wg * 4 + mi) * 4 + ni) * 64 + lane) * 4);
      acc[mi][ni] += o;
#pragma unroll
      for (int r = 0; r < 4; r++) {
        const int row = mb + wm + mi * 16 + rb + r;
        const int col = nb + wn + ni * 16 + fr;
        float v = acc[mi][ni][r];
        if (EPI == 3) {
          if (col < DH) C0[(size_t)row * DH + col] = f2bf(v + bias[col]);
          else          C1[(size_t)row * DH + (col - DH)] = f2bf(v);
        } else if (EPI == 2) {
          C0[(size_t)row * ldc + col] = f2bf(v);
        } else if (EPI == 1) {
          v += bias[col];
          if ((col >> 9) == 0) {
            const float s = 1.0f / (1.0f + expf(-v));
            v = 1.0f / (base_tau[col & (DH - 1)] * 2.0f * s + 1e-8f);  // tau_inv
          } else {
            v = 1.0f + 0.5f * tanhf(v);                                 // A_row/B_col
          }
          C0[(size_t)row * ldc + col] = f2bf(v);
        }
      }
    }
  }
}

// ---- fused G1|GB: [x|h] @ [W1 | base_B~] -> pre1, rawB. XCD-swizzled ----
__global__ __launch_bounds__(512, 4) void fused_gemm_k(
    const unsigned short* __restrict__ xbf,
    const unsigned short* __restrict__ hbf,
    const unsigned short* __restrict__ BTcat,
    unsigned short* __restrict__ pre1,
    unsigned short* __restrict__ rawB,
    const float* __restrict__ b1)
{
  __shared__ __align__(16) char smem[65536];
  const int cpx = gridDim.x >> 3;                             // 512/8 = 64
  const int virt = (blockIdx.x & 7) * cpx + (blockIdx.x >> 3);
  const int mb = (virt & 63) * 128;
  const int nb = (virt >> 6) * 128;
  gemm2_engine<3>(xbf, DIN, DIN, hbf, DH, BTcat, DIN + DH,
                  pre1, DH, rawB, b1, nullptr, mb, nb, DIN + DH, smem);
}

// ---- merged tail: blocks [0,768) G2 scales; [768,1024) GA rawA ----
__global__ __launch_bounds__(512, 4) void tail_gemm_k(
    const unsigned short* __restrict__ hbf,
    const unsigned short* __restrict__ Abf,
    const unsigned short* __restrict__ tbf,
    const unsigned short* __restrict__ W2T,
    unsigned short* __restrict__ rawA,
    unsigned short* __restrict__ scales,
    const float* __restrict__ b2,
    const float* __restrict__ base_tau)
{
  __shared__ __align__(16) char smem[65536];
  const int b = blockIdx.x;
  if (b < 768) {
    const int mb = (b & 63) * 128, nb = (b >> 6) * 128;      // N = 12*128 = 1536
    gemm2_engine<1>(tbf, DH, DH, nullptr, 0, W2T, DH,
                    scales, 3 * DH, nullptr, b2, base_tau, mb, nb, DH, smem);
  } else {
    const int b2i = b - 768;
    const int mb = (b2i & 63) * 128, nb = (b2i >> 6) * 128;  // N = 4*128 = 512
    gemm2_engine<2>(hbf, DH, DH, nullptr, 0, Abf, DH,
                    rawA, DH, nullptr, nullptr, nullptr, mb, nb, DH, smem);
  }
}

// ---------- block-wide sum over 256 threads (4 waves) ----------
__device__ __forceinline__ float block_sum256(float v, float* red) {
#pragma unroll
  for (int m = 32; m >= 1; m >>= 1) v += __shfl_xor(v, m, 64);
  __syncthreads();
  if ((threadIdx.x & 63) == 0) red[threadIdx.x >> 6] = v;
  __syncthreads();
  return red[0] + red[1] + red[2] + red[3];
}

// ---------- t = bf16(gelu_exact(LN(pre1))) ----------
__global__ __launch_bounds__(256) void ln_gelu_k(
    const unsigned short* __restrict__ pre,
    const float* __restrict__ g, const float* __restrict__ b,
    unsigned short* __restrict__ t)
{
  __shared__ float red[4];
  const int row = blockIdx.x;
  const int c = threadIdx.x * 2;
  const size_t ro = (size_t)row * DH;
  u16x2 raw = *(const u16x2*)(pre + ro + c);
  const float v0 = bf2f(raw[0]), v1 = bf2f(raw[1]);
  const float mu = block_sum256(v0 + v1, red) * (1.0f / DH);
  const float d0 = v0 - mu, d1 = v1 - mu;
  const float var = block_sum256(d0 * d0 + d1 * d1, red) * (1.0f / DH);
  const float inv = rsqrtf(var + 1e-5f);
  const float y0 = d0 * inv * g[c] + b[c];
  const float y1 = d1 * inv * g[c + 1] + b[c + 1];
  u16x2 o = { f2bf(0.5f * y0 * (1.0f + erff(y0 * 0.70710678118f))),
              f2bf(0.5f * y1 * (1.0f + erff(y1 * 0.70710678118f))) };
  *(u16x2*)(t + ro + c) = o;
}

// ---------- new_h = LN(h + dt*(-h*tauinv + tanh(rawA*arow + rawB*bcol))) ----------
__global__ __launch_bounds__(256) void final_k(
    const float* __restrict__ h,
    const unsigned short* __restrict__ rawA,
    const unsigned short* __restrict__ rawB,
    const unsigned short* __restrict__ scales,
    const float* __restrict__ hn_g, const float* __restrict__ hn_b,
    float* __restrict__ out)
{
  __shared__ float red[4];
  const int row = blockIdx.x;
  const int c = threadIdx.x * 2;
  const size_t ro = (size_t)row * DH;
  f32x2 hv = *(const f32x2*)(h + ro + c);
  u16x2 ra = *(const u16x2*)(rawA + ro + c);
  u16x2 rb = *(const u16x2*)(rawB + ro + c);
  const unsigned short* sc = scales + (size_t)row * (3 * DH);
  u16x2 ti  = *(const u16x2*)(sc + c);
  u16x2 arw = *(const u16x2*)(sc + DH + c);
  u16x2 bcl = *(const u16x2*)(sc + 2 * DH + c);
  const float u0 = hv[0] + 0.1f * (-hv[0] * bf2f(ti[0])
                 + tanhf(bf2f(ra[0]) * bf2f(arw[0]) + bf2f(rb[0]) * bf2f(bcl[0])));
  const float u1 = hv[1] + 0.1f * (-hv[1] * bf2f(ti[1])
                 + tanhf(bf2f(ra[1]) * bf2f(arw[1]) + bf2f(rb[1]) * bf2f(bcl[1])));
  const float mu = block_sum256(u0 + u1, red) * (1.0f / DH);
  const float d0 = u0 - mu, d1 = u1 - mu;
  const float var = block_sum256(d0 * d0 + d1 * d1, red) * (1.0f / DH);
  const float inv = rsqrtf(var + 1e-5f);
  f32x2 o = { d0 * inv * hn_g[c] + hn_b[c],
              d1 * inv * hn_g[c + 1] + hn_b[c + 1] };
  *(f32x2*)(out + ro + c) = o;
}

extern "C" void kernel_launch(void* const* d_in, const int* in_sizes, int n_in,
                              void* d_out, int out_size, void* d_ws, size_t ws_size,
                              hipStream_t stream)
{
  const float* x        = (const float*)d_in[0];
  const float* h        = (const float*)d_in[1];
  const float* W1       = (const float*)d_in[2];   // [4608][512]
  const float* b1       = (const float*)d_in[3];
  const float* ln1_g    = (const float*)d_in[4];
  const float* ln1_b    = (const float*)d_in[5];
  const float* W2       = (const float*)d_in[6];   // [512][1536]
  const float* b2       = (const float*)d_in[7];
  const float* base_tau = (const float*)d_in[8];
  const float* base_A   = (const float*)d_in[9];   // [512][512]
  const float* base_B   = (const float*)d_in[10];  // [4096][512]
  const float* hn_g     = (const float*)d_in[11];
  const float* hn_b     = (const float*)d_in[12];

  char* w = (char*)d_ws;
  // ws layout (bytes), total 128,974,848 (== proven-safe footprint):
  unsigned short* xbf    = (unsigned short*)(w);               // [8192][4096] 67,108,864
  unsigned short* hbf    = (unsigned short*)(w + 67108864);    // [8192][512]   8,388,608
  unsigned short* BTcat  = (unsigned short*)(w + 75497472);    // [1024][4608]  9,437,184
  unsigned short* tbf    = (unsigned short*)(w + 75497472);    // ALIAS over BTcat (dead after fused GEMM)
  unsigned short* W2T    = (unsigned short*)(w + 84934656);    // [1536][512]   1,572,864
  unsigned short* Abf    = (unsigned short*)(w + 86507520);    // [512][512]      524,288
  unsigned short* pre1   = (unsigned short*)(w + 87031808);    // [8192][512]   8,388,608
  unsigned short* rawA   = (unsigned short*)(w + 87031808);    // ALIAS over pre1 (dead after ln_gelu)
  unsigned short* rawB   = (unsigned short*)(w + 95420416);    // [8192][512]   8,388,608
  unsigned short* scales = (unsigned short*)(w + 103809024);   // [8192][1536] 25,165,824

  // ---- prep: big x cast + merged small prep ----
  cast_bf16_k<<<DIN * BATCH / 1024, 256, 0, stream>>>(x, xbf);
  prep_small_k<<<9600, 256, 0, stream>>>(h, hbf, base_A, Abf, W1, base_B, BTcat, W2, W2T);

  // ---- fused G1|GB -> pre1, rawB ----
  fused_gemm_k<<<512, 512, 0, stream>>>(xbf, hbf, BTcat, pre1, rawB, b1);
  // ---- t = gelu(LN(pre1)) -> tbf ----
  ln_gelu_k<<<BATCH, 256, 0, stream>>>(pre1, ln1_g, ln1_b, tbf);
  // ---- merged tail: scales = transforms(t @ W2 + b2); rawA = h @ base_A^T ----
  tail_gemm_k<<<1024, 512, 0, stream>>>(hbf, Abf, tbf, W2T, rawA, scales, b2, base_tau);
  // ---- final: dhdt + LN -> f32 out ----
  final_k<<<BATCH, 256, 0, stream>>>(h, rawA, rawB, scales, hn_g, hn_b, (float*)d_out);
}